// Round 3
// baseline (309.466 us; speedup 1.0000x reference)
//
#include <hip/hip_runtime.h>
#include <math.h>

// -----------------------------------------------------------------------------
// ScoreEntropyDiscreteDiffusion q_sample + Gumbel-max sampling.
// OUTPUT DTYPE IS FLOAT32 (rounds 0-2 wrongly wrote packed bf16 -> the 18.5s).
//
// Structure: Q = ones/K  =>  einsum = (sum p)/32 broadcast; log_x0 has two
// values (hot=0.0f, cold=log(1e-8f)), so the 64-step scan state is two
// scalars per hot-bin-position h (h fixes the f32 summation order of the
// einsum). Faithful f32 emulation: __f*_rn ops (no FMA contraction),
// correctly-rounded f32 transcendentals via f64 libm.
// Output = log(one_hot(argmax(log_p + g)) + 1e-8): 0.0f at argmax, cold
// constant elsewhere; only the per-feature argmax must match the np ref.
// -----------------------------------------------------------------------------

__device__ __forceinline__ float cr_logf32(float x) {
    return (float)log((double)x);   // correctly-rounded f32 log
}
__device__ __forceinline__ float cr_expf32(float x) {
    return (float)exp((double)x);
}

// traj layout in d_ws: float lh[32], lc[32], coldv (index 64)
__global__ void traj_kernel(const float* __restrict__ log_x0,
                            const int* __restrict__ t_ptr,
                            float* __restrict__ traj) {
    __shared__ float sig[1000];
    __shared__ float init2[2];
    int t = *t_ptr;
    if (t > 1000) t = 1000;

    if (threadIdx.x == 0) {
        float hotf = -1e30f, coldf = 1e30f;
        for (int j = 0; j < 32; ++j) {
            float v = log_x0[j];
            hotf = fmaxf(hotf, v);
            coldf = fminf(coldf, v);
        }
        init2[0] = hotf;
        init2[1] = coldf;
        traj[64] = coldf;                        // output cold value (f32)
        // sigmas, faithful f32: ((s/1000 + 0.008)/1.008 * pi) * 0.5 ; cos^2
        float ac_prev = 0.0f;
        for (int s = 0; s <= t; ++s) {
            float a = __fdiv_rn((float)s, 1000.0f);
            float b = __fadd_rn(a, 0.008f);
            float c = __fdiv_rn(b, 1.008f);
            float d = __fmul_rn(c, 0x1.921fb6p+1f);  // fl32(pi)
            float e = __fmul_rn(d, 0.5f);
            float cs = (float)cos((double)e);        // CR f32 cos
            float ac = __fmul_rn(cs, cs);
            if (s > 0) sig[s - 1] = __fsub_rn(1.0f, __fdiv_rn(ac, ac_prev));
            ac_prev = ac;
        }
    }
    __syncthreads();

    if (threadIdx.x < 32) {
        const int h = threadIdx.x;   // hot-bin position (einsum sum order)
        float lh = init2[0];
        float lc = init2[1];
        for (int k = 0; k < t; ++k) {
            float sg = sig[k];
            float ph = cr_expf32(lh);
            float pc = cr_expf32(lc);
            float th = __fmul_rn(ph, 0.03125f);   // exact (exp shift)
            float tc = __fmul_rn(pc, 0.03125f);
            float acc = 0.0f;
            for (int i = 0; i < 32; ++i)
                acc = __fadd_rn(acc, (i == h) ? th : tc);
            float s1  = __fsub_rn(1.0f, sg);
            float sm  = __fmul_rn(sg, acc);
            float phn = __fadd_rn(__fmul_rn(s1, ph), sm);
            float pcn = __fadd_rn(__fmul_rn(s1, pc), sm);
            lh = cr_logf32(__fadd_rn(phn, 1e-8f));
            lc = cr_logf32(__fadd_rn(pcn, 1e-8f));
        }
        traj[h]      = lh;
        traj[32 + h] = lc;
    }
}

__global__ void sample_kernel(const float* __restrict__ log_x0,
                              const float* __restrict__ u,
                              const float* __restrict__ traj,
                              float* __restrict__ out,
                              int nfeat) {
    __shared__ float lh_s[32], lc_s[32];
    __shared__ float coldv_s;
    if (threadIdx.x < 32) {
        lh_s[threadIdx.x] = traj[threadIdx.x];
        lc_s[threadIdx.x] = traj[32 + threadIdx.x];
    }
    if (threadIdx.x == 0) coldv_s = traj[64];
    __syncthreads();
    const float coldv = coldv_s;

    const int lane32  = threadIdx.x & 31;
    const int group   = (int)((blockIdx.x * blockDim.x + threadIdx.x) >> 5);
    const int ngroups = (int)((gridDim.x * blockDim.x) >> 5);
    const int shift   = (threadIdx.x & 32) ? 32 : 0;

    for (int f = group; f < nfeat; f += ngroups) {
        const int base = f * 32 + lane32;
        const float uf = u[base];        // coalesced
        const float lx = log_x0[base];   // coalesced
        const bool hot = lx > -1.0f;

        unsigned long long bal = __ballot(hot);
        unsigned mm = (unsigned)(bal >> shift);
        int h = mm ? (__ffs(mm) - 1) : 0;

        float L = hot ? lh_s[h] : lc_s[h];

        // g = -log(-log(u + 1e-30) + 1e-30), f32 rounding at each op boundary
        float c0 = __fadd_rn(uf, 1e-30f);
        float t2 = cr_logf32(c0);
        float t3 = __fadd_rn(-t2, 1e-30f);
        float t4 = cr_logf32(t3);
        float g  = -t4;
        float s  = __fadd_rn(L, g);      // f32 score, as reference

        // 32-lane butterfly argmax, first-index tie-break (np.argmax)
        int idx = lane32;
        #pragma unroll
        for (int m = 16; m > 0; m >>= 1) {
            float os = __shfl_xor(s,   m, 32);
            int   oi = __shfl_xor(idx, m, 32);
            if (os > s || (os == s && oi < idx)) {
                s = os;
                idx = oi;
            }
        }
        out[base] = (lane32 == idx) ? 0.0f : coldv;   // coalesced f32 stores
    }
}

extern "C" void kernel_launch(void* const* d_in, const int* in_sizes, int n_in,
                              void* d_out, int out_size, void* d_ws, size_t ws_size,
                              hipStream_t stream) {
    const float* log_x0 = (const float*)d_in[0];
    const float* u      = (const float*)d_in[1];
    const int*   t_ptr  = (const int*)d_in[2];
    float* out = (float*)d_out;
    float* traj = (float*)d_ws;

    const int nfeat = in_sizes[0] / 32;   // B*F = 1,048,576

    traj_kernel<<<1, 64, 0, stream>>>(log_x0, t_ptr, traj);

    sample_kernel<<<2048, 256, 0, stream>>>(log_x0, u, traj, out, nfeat);
}

// Round 4
// 135.836 us; speedup vs baseline: 2.2782x; 2.2782x over previous
//
#include <hip/hip_runtime.h>
#include <math.h>

// -----------------------------------------------------------------------------
// Round 4: same proven numerics, 10x less transcendental work.
// Key insight: among the 31 cold bins (identical base log-prob lc) the score
// order equals the u order (g = -log(-log(u+1e-30)+1e-30) is monotone in u and
// identical for identical u). So per feature we need only the cold max-u (+its
// first index), the hot bin's u, and ONE hot-vs-cold compare -> 2 fast g-evals
// per feature instead of 32 correctly-rounded f64 ones. Features whose compare
// margin < 1e-3 or whose cold top-2 u-gap < 1e-4 (ties/plateaus) fall back to
// the exact round-3 CR-f64 per-bin path (~0.4% of features).
// -----------------------------------------------------------------------------

__device__ __forceinline__ float cr_logf32(float x) { return (float)log((double)x); }

__device__ __forceinline__ float fast_g(float u) {
    float c0 = u + 1e-30f;
    float t2 = __logf(c0);          // fast HW log, abs err on g <= ~1e-5
    float t3 = 1e-30f - t2;
    float t4 = __logf(t3);
    return -t4;
}

__device__ __forceinline__ float cr_g(float u) {
    float c0 = __fadd_rn(u, 1e-30f);
    float t2 = cr_logf32(c0);
    float t3 = __fadd_rn(-t2, 1e-30f);
    float t4 = cr_logf32(t3);
    return -t4;
}

// traj layout in d_ws: float lh[32], lc[32], coldv (index 64)
__global__ void traj_kernel(const float* __restrict__ log_x0,
                            const int* __restrict__ t_ptr,
                            float* __restrict__ traj) {
    __shared__ float ac[1001];
    __shared__ float sig[1000];
    __shared__ float init2[2];
    int t = *t_ptr;
    if (t > 1000) t = 1000;
    if (t < 0) t = 0;

    // parallel faithful-f32 cosine schedule (CR f32 cos via f64)
    for (int s = threadIdx.x; s <= t; s += blockDim.x) {
        float a = __fdiv_rn((float)s, 1000.0f);
        float b = __fadd_rn(a, 0.008f);
        float c = __fdiv_rn(b, 1.008f);
        float d = __fmul_rn(c, 0x1.921fb6p+1f);  // fl32(pi)
        float e = __fmul_rn(d, 0.5f);
        float cs = (float)cos((double)e);
        ac[s] = __fmul_rn(cs, cs);
    }
    if (threadIdx.x == 0) {
        float hotf = -1e30f, coldf = 1e30f;
        for (int j = 0; j < 32; ++j) {
            float v = log_x0[j];
            hotf = fmaxf(hotf, v);
            coldf = fminf(coldf, v);
        }
        init2[0] = hotf;
        init2[1] = coldf;
        traj[64] = coldf;
    }
    __syncthreads();
    for (int s = threadIdx.x + 1; s <= t; s += blockDim.x)
        sig[s - 1] = __fsub_rn(1.0f, __fdiv_rn(ac[s], ac[s - 1]));
    __syncthreads();

    if (threadIdx.x < 32) {
        const int h = threadIdx.x;   // hot-bin position (einsum f32 sum order)
        float lh = init2[0];
        float lc = init2[1];
        for (int k = 0; k < t; ++k) {
            float sg = sig[k];
            float ph = (float)exp((double)lh);
            float pc = (float)exp((double)lc);
            float th = __fmul_rn(ph, 0.03125f);
            float tc = __fmul_rn(pc, 0.03125f);
            float acc = 0.0f;
            for (int i = 0; i < 32; ++i)
                acc = __fadd_rn(acc, (i == h) ? th : tc);
            float s1  = __fsub_rn(1.0f, sg);
            float sm  = __fmul_rn(sg, acc);
            float phn = __fadd_rn(__fmul_rn(s1, ph), sm);
            float pcn = __fadd_rn(__fmul_rn(s1, pc), sm);
            lh = cr_logf32(__fadd_rn(phn, 1e-8f));
            lc = cr_logf32(__fadd_rn(pcn, 1e-8f));
        }
        traj[h]      = lh;
        traj[32 + h] = lc;
    }
}

__global__ void sample_kernel(const float4* __restrict__ log_x0,
                              const float4* __restrict__ u,
                              const float* __restrict__ traj,
                              float4* __restrict__ out,
                              int nfeat) {
    __shared__ float lh_s[32], lc_s[32];
    __shared__ float coldv_s;
    if (threadIdx.x < 32) {
        lh_s[threadIdx.x] = traj[threadIdx.x];
        lc_s[threadIdx.x] = traj[32 + threadIdx.x];
    }
    if (threadIdx.x == 0) coldv_s = traj[64];
    __syncthreads();
    const float coldv = coldv_s;

    const int lane8 = threadIdx.x & 7;                       // lane in 8-lane group
    const int g0 = (int)((blockIdx.x * blockDim.x + threadIdx.x) >> 3);
    const int gs = (int)((gridDim.x * blockDim.x) >> 3);

    for (int f = g0; f < nfeat; f += gs) {
        const int vbase = f * 8 + lane8;                     // float4 index
        const float4 u4 = u[vbase];                          // 16B coalesced
        const float4 x4 = log_x0[vbase];

        const float uu0 = u4.x, uu1 = u4.y, uu2 = u4.z, uu3 = u4.w;
        const bool  h0 = x4.x > -1.0f, h1 = x4.y > -1.0f,
                    h2 = x4.z > -1.0f, h3 = x4.w > -1.0f;

        // local top-2 cold u (first-index tie-break via strict >), hot pos/u
        int   hloc = -1;  float uhot = -1.0f;
        float t1u  = -1.0f; int t1i = 0; float t2u = -1.0f;
        const int ib = lane8 * 4;
        if (h0) { hloc = ib;   uhot = uu0; } else { t1u = uu0; t1i = ib; }
        if (h1) { hloc = ib+1; uhot = uu1; }
        else if (uu1 > t1u) { t2u = t1u; t1u = uu1; t1i = ib+1; }
        else if (uu1 > t2u) { t2u = uu1; }
        if (h2) { hloc = ib+2; uhot = uu2; }
        else if (uu2 > t1u) { t2u = t1u; t1u = uu2; t1i = ib+2; }
        else if (uu2 > t2u) { t2u = uu2; }
        if (h3) { hloc = ib+3; uhot = uu3; }
        else if (uu3 > t1u) { t2u = t1u; t1u = uu3; t1i = ib+3; }
        else if (uu3 > t2u) { t2u = uu3; }

        // 3-step merge across the 8-lane group
        #pragma unroll
        for (int m = 1; m < 8; m <<= 1) {
            float o1u = __shfl_xor(t1u, m);
            int   o1i = __shfl_xor(t1i, m);
            float o2u = __shfl_xor(t2u, m);
            int   ohl = __shfl_xor(hloc, m);
            float ouh = __shfl_xor(uhot, m);
            if (o1u > t1u)       { t2u = fmaxf(t1u, o2u); t1u = o1u; t1i = o1i; }
            else if (o1u == t1u) { t1i = min(t1i, o1i); t2u = t1u; }   // tie -> careful
            else                 { t2u = fmaxf(t2u, o1u); }
            hloc = max(hloc, ohl);
            uhot = fmaxf(uhot, ouh);
        }

        const int h = (hloc < 0) ? 0 : hloc;
        const float lh = lh_s[h];
        const float lc = lc_s[h];

        // fast hot-vs-cold compare
        const float s_hot  = lh + fast_g(uhot);
        const float s_cold = lc + fast_g(t1u);
        const float margin = s_hot - s_cold;
        int widx = (margin > 0.0f) ? h : t1i;

        const bool careful = (fabsf(margin) < 1e-3f) | ((t1u - t2u) < 1e-4f) | (hloc < 0);
        if (__builtin_expect(careful, 0)) {
            // exact round-3 path: CR-f64 g for all 4 local bins, wave argmax
            float bs = -3.0e38f; int bi = 0;
            float s;
            s = __fadd_rn(h0 ? lh : lc, cr_g(uu0));
            if (s > bs) { bs = s; bi = ib; }
            s = __fadd_rn(h1 ? lh : lc, cr_g(uu1));
            if (s > bs) { bs = s; bi = ib+1; }
            s = __fadd_rn(h2 ? lh : lc, cr_g(uu2));
            if (s > bs) { bs = s; bi = ib+2; }
            s = __fadd_rn(h3 ? lh : lc, cr_g(uu3));
            if (s > bs) { bs = s; bi = ib+3; }
            #pragma unroll
            for (int m = 1; m < 8; m <<= 1) {
                float os = __shfl_xor(bs, m);
                int   oi = __shfl_xor(bi, m);
                if (os > bs || (os == bs && oi < bi)) { bs = os; bi = oi; }
            }
            widx = bi;
        }

        float4 o;
        o.x = (ib     == widx) ? 0.0f : coldv;
        o.y = (ib + 1 == widx) ? 0.0f : coldv;
        o.z = (ib + 2 == widx) ? 0.0f : coldv;
        o.w = (ib + 3 == widx) ? 0.0f : coldv;
        out[vbase] = o;                                      // 16B coalesced
    }
}

extern "C" void kernel_launch(void* const* d_in, const int* in_sizes, int n_in,
                              void* d_out, int out_size, void* d_ws, size_t ws_size,
                              hipStream_t stream) {
    const float* log_x0 = (const float*)d_in[0];
    const float* u      = (const float*)d_in[1];
    const int*   t_ptr  = (const int*)d_in[2];
    float* out  = (float*)d_out;
    float* traj = (float*)d_ws;

    const int nfeat = in_sizes[0] / 32;   // B*F = 1,048,576

    traj_kernel<<<1, 128, 0, stream>>>(log_x0, t_ptr, traj);

    sample_kernel<<<2048, 256, 0, stream>>>((const float4*)log_x0,
                                            (const float4*)u, traj,
                                            (float4*)out, nfeat);
}

// Round 8
// 135.748 us; speedup vs baseline: 2.2797x; 1.0007x over previous
//
#include <hip/hip_runtime.h>
#include <math.h>

// -----------------------------------------------------------------------------
// Round 8 = round 4 (measured-good: passed, 120us, profiled 3x) with ONE delta:
// fast_g hardened near u->1 (piecewise log1p-Horner for u>=0.9). Rounds 5-7
// all timed out on the same pod handle with no test output — including round 7
// which was structurally identical to round 4 — so this resubmission is the
// infra-vs-code disambiguator: minimal delta from known-good.
//
// Numerics (proven round 3/4): f32-faithful scan -> (lh,lc) per hot position;
// cold-bin score order == u order; one hot-vs-cold compare; guarded fallback
// to exact CR-f64 per-bin path (bit-faithful to np ref).
// -----------------------------------------------------------------------------

__device__ __forceinline__ float cr_logf32(float x) { return (float)log((double)x); }

__device__ __forceinline__ float fast_g(float u) {
    // t3 = -log(u + 1e-30), piecewise:
    //   u >= 0.9: -log1p(u-1) via 6-term Horner in w=u-1 (rel err ~5e-7;
    //             fixes __logf's ~5e-7 ABSOLUTE error blowing up as u->1)
    //   u <  0.9: 1e-30 - __logf(u+1e-30)  (t3 >= 0.105 -> rel err <= ~5e-6)
    float w   = u - 1.0f;                      // exact for u in [0.5, 1]
    float p   = w * (1.0f - w * (0.5f - w * (0.33333334f - w * (0.25f -
                w * (0.2f - w * 0.16666667f)))));   // log1p(w), |w|<=0.1
    float t3p = 1e-30f - p;
    float t3l = 1e-30f - __logf(u + 1e-30f);
    float t3  = (u >= 0.9f) ? t3p : t3l;
    return -__logf(t3);
}

__device__ __forceinline__ float cr_g(float u) {
    float c0 = __fadd_rn(u, 1e-30f);
    float t2 = cr_logf32(c0);
    float t3 = __fadd_rn(-t2, 1e-30f);
    float t4 = cr_logf32(t3);
    return -t4;
}

// traj layout in d_ws: float lh[32], lc[32], coldv (index 64)
__global__ void traj_kernel(const float* __restrict__ log_x0,
                            const int* __restrict__ t_ptr,
                            float* __restrict__ traj) {
    __shared__ float ac[1001];
    __shared__ float sig[1000];
    __shared__ float init2[2];
    int t = *t_ptr;
    if (t > 1000) t = 1000;
    if (t < 0) t = 0;

    // parallel faithful-f32 cosine schedule (CR f32 cos via f64)
    for (int s = threadIdx.x; s <= t; s += blockDim.x) {
        float a = __fdiv_rn((float)s, 1000.0f);
        float b = __fadd_rn(a, 0.008f);
        float c = __fdiv_rn(b, 1.008f);
        float d = __fmul_rn(c, 0x1.921fb6p+1f);  // fl32(pi)
        float e = __fmul_rn(d, 0.5f);
        float cs = (float)cos((double)e);
        ac[s] = __fmul_rn(cs, cs);
    }
    if (threadIdx.x == 0) {
        float hotf = -1e30f, coldf = 1e30f;
        for (int j = 0; j < 32; ++j) {
            float v = log_x0[j];
            hotf = fmaxf(hotf, v);
            coldf = fminf(coldf, v);
        }
        init2[0] = hotf;
        init2[1] = coldf;
        traj[64] = coldf;
    }
    __syncthreads();
    for (int s = threadIdx.x + 1; s <= t; s += blockDim.x)
        sig[s - 1] = __fsub_rn(1.0f, __fdiv_rn(ac[s], ac[s - 1]));
    __syncthreads();

    if (threadIdx.x < 32) {
        const int h = threadIdx.x;   // hot-bin position (einsum f32 sum order)
        float lh = init2[0];
        float lc = init2[1];
        for (int k = 0; k < t; ++k) {
            float sg = sig[k];
            float ph = (float)exp((double)lh);
            float pc = (float)exp((double)lc);
            float th = __fmul_rn(ph, 0.03125f);
            float tc = __fmul_rn(pc, 0.03125f);
            float acc = 0.0f;
            for (int i = 0; i < 32; ++i)
                acc = __fadd_rn(acc, (i == h) ? th : tc);
            float s1  = __fsub_rn(1.0f, sg);
            float sm  = __fmul_rn(sg, acc);
            float phn = __fadd_rn(__fmul_rn(s1, ph), sm);
            float pcn = __fadd_rn(__fmul_rn(s1, pc), sm);
            lh = cr_logf32(__fadd_rn(phn, 1e-8f));
            lc = cr_logf32(__fadd_rn(pcn, 1e-8f));
        }
        traj[h]      = lh;
        traj[32 + h] = lc;
    }
}

__global__ void sample_kernel(const float4* __restrict__ log_x0,
                              const float4* __restrict__ u,
                              const float* __restrict__ traj,
                              float4* __restrict__ out,
                              int nfeat) {
    __shared__ float lh_s[32], lc_s[32];
    __shared__ float coldv_s;
    if (threadIdx.x < 32) {
        lh_s[threadIdx.x] = traj[threadIdx.x];
        lc_s[threadIdx.x] = traj[32 + threadIdx.x];
    }
    if (threadIdx.x == 0) coldv_s = traj[64];
    __syncthreads();
    const float coldv = coldv_s;

    const int lane8 = threadIdx.x & 7;                       // lane in 8-lane group
    const int g0 = (int)((blockIdx.x * blockDim.x + threadIdx.x) >> 3);
    const int gs = (int)((gridDim.x * blockDim.x) >> 3);

    for (int f = g0; f < nfeat; f += gs) {
        const int vbase = f * 8 + lane8;                     // float4 index
        const float4 u4 = u[vbase];                          // 16B coalesced
        const float4 x4 = log_x0[vbase];

        const float uu0 = u4.x, uu1 = u4.y, uu2 = u4.z, uu3 = u4.w;
        const bool  h0 = x4.x > -1.0f, h1 = x4.y > -1.0f,
                    h2 = x4.z > -1.0f, h3 = x4.w > -1.0f;

        // local top-2 cold u (first-index tie-break via strict >), hot pos/u
        int   hloc = -1;  float uhot = -1.0f;
        float t1u  = -1.0f; int t1i = 0; float t2u = -1.0f;
        const int ib = lane8 * 4;
        if (h0) { hloc = ib;   uhot = uu0; } else { t1u = uu0; t1i = ib; }
        if (h1) { hloc = ib+1; uhot = uu1; }
        else if (uu1 > t1u) { t2u = t1u; t1u = uu1; t1i = ib+1; }
        else if (uu1 > t2u) { t2u = uu1; }
        if (h2) { hloc = ib+2; uhot = uu2; }
        else if (uu2 > t1u) { t2u = t1u; t1u = uu2; t1i = ib+2; }
        else if (uu2 > t2u) { t2u = uu2; }
        if (h3) { hloc = ib+3; uhot = uu3; }
        else if (uu3 > t1u) { t2u = t1u; t1u = uu3; t1i = ib+3; }
        else if (uu3 > t2u) { t2u = uu3; }

        // 3-step merge across the 8-lane group
        #pragma unroll
        for (int m = 1; m < 8; m <<= 1) {
            float o1u = __shfl_xor(t1u, m);
            int   o1i = __shfl_xor(t1i, m);
            float o2u = __shfl_xor(t2u, m);
            int   ohl = __shfl_xor(hloc, m);
            float ouh = __shfl_xor(uhot, m);
            if (o1u > t1u)       { t2u = fmaxf(t1u, o2u); t1u = o1u; t1i = o1i; }
            else if (o1u == t1u) { t1i = min(t1i, o1i); t2u = t1u; }   // tie -> careful
            else                 { t2u = fmaxf(t2u, o1u); }
            hloc = max(hloc, ohl);
            uhot = fmaxf(uhot, ouh);
        }

        const int h = (hloc < 0) ? 0 : hloc;
        const float lh = lh_s[h];
        const float lc = lc_s[h];

        // fast hot-vs-cold compare
        const float s_hot  = lh + fast_g(uhot);
        const float s_cold = lc + fast_g(t1u);
        const float margin = s_hot - s_cold;
        int widx = (margin > 0.0f) ? h : t1i;

        const bool careful = (fabsf(margin) < 1e-3f) | ((t1u - t2u) < 1e-4f) | (hloc < 0);
        if (__builtin_expect(careful, 0)) {
            // exact round-3 path: CR-f64 g for all 4 local bins, wave argmax
            float bs = -3.0e38f; int bi = 0;
            float s;
            s = __fadd_rn(h0 ? lh : lc, cr_g(uu0));
            if (s > bs) { bs = s; bi = ib; }
            s = __fadd_rn(h1 ? lh : lc, cr_g(uu1));
            if (s > bs) { bs = s; bi = ib+1; }
            s = __fadd_rn(h2 ? lh : lc, cr_g(uu2));
            if (s > bs) { bs = s; bi = ib+2; }
            s = __fadd_rn(h3 ? lh : lc, cr_g(uu3));
            if (s > bs) { bs = s; bi = ib+3; }
            #pragma unroll
            for (int m = 1; m < 8; m <<= 1) {
                float os = __shfl_xor(bs, m);
                int   oi = __shfl_xor(bi, m);
                if (os > bs || (os == bs && oi < bi)) { bs = os; bi = oi; }
            }
            widx = bi;
        }

        float4 o;
        o.x = (ib     == widx) ? 0.0f : coldv;
        o.y = (ib + 1 == widx) ? 0.0f : coldv;
        o.z = (ib + 2 == widx) ? 0.0f : coldv;
        o.w = (ib + 3 == widx) ? 0.0f : coldv;
        out[vbase] = o;                                      // 16B coalesced
    }
}

extern "C" void kernel_launch(void* const* d_in, const int* in_sizes, int n_in,
                              void* d_out, int out_size, void* d_ws, size_t ws_size,
                              hipStream_t stream) {
    const float* log_x0 = (const float*)d_in[0];
    const float* u      = (const float*)d_in[1];
    const int*   t_ptr  = (const int*)d_in[2];
    float* out  = (float*)d_out;
    float* traj = (float*)d_ws;

    const int nfeat = in_sizes[0] / 32;   // B*F = 1,048,576

    traj_kernel<<<1, 128, 0, stream>>>(log_x0, t_ptr, traj);

    sample_kernel<<<2048, 256, 0, stream>>>((const float4*)log_x0,
                                            (const float4*)u, traj,
                                            (float4*)out, nfeat);
}

// Round 10
// 135.239 us; speedup vs baseline: 2.2883x; 1.0038x over previous
//
#include <hip/hip_runtime.h>
#include <math.h>

// -----------------------------------------------------------------------------
// Round 10 = round 8's measured-good kernel (passed 2x: rounds 4 & 8, ~120us)
// with ONE delta: 2x feature unroll in the grid-stride loop. Both features'
// loads issue before either reduction chain runs -> doubles memory-level
// parallelism (the identified limiter: VALUBusy 38%, hbm 28%, latency-bound).
// The per-feature reduction body is byte-identical to round 8's.
//
// Numerics (proven rounds 3/4/8): f32-faithful scan -> (lh,lc) per hot-bin
// position h; cold-bin score order == u order; one hot-vs-cold compare with
// hardened fast_g; guarded fallback to exact CR-f64 per-bin path.
// -----------------------------------------------------------------------------

__device__ __forceinline__ float cr_logf32(float x) { return (float)log((double)x); }

__device__ __forceinline__ float fast_g(float u) {
    // t3 = -log(u + 1e-30), piecewise (hardened near u->1):
    float w   = u - 1.0f;                      // exact for u in [0.5, 1]
    float p   = w * (1.0f - w * (0.5f - w * (0.33333334f - w * (0.25f -
                w * (0.2f - w * 0.16666667f)))));   // log1p(w), |w|<=0.1
    float t3p = 1e-30f - p;
    float t3l = 1e-30f - __logf(u + 1e-30f);
    float t3  = (u >= 0.9f) ? t3p : t3l;
    return -__logf(t3);
}

__device__ __forceinline__ float cr_g(float u) {
    float c0 = __fadd_rn(u, 1e-30f);
    float t2 = cr_logf32(c0);
    float t3 = __fadd_rn(-t2, 1e-30f);
    float t4 = cr_logf32(t3);
    return -t4;
}

// traj layout in d_ws: float lh[32], lc[32], coldv (index 64)
__global__ void traj_kernel(const float* __restrict__ log_x0,
                            const int* __restrict__ t_ptr,
                            float* __restrict__ traj) {
    __shared__ float ac[1001];
    __shared__ float sig[1000];
    __shared__ float init2[2];
    int t = *t_ptr;
    if (t > 1000) t = 1000;
    if (t < 0) t = 0;

    for (int s = threadIdx.x; s <= t; s += blockDim.x) {
        float a = __fdiv_rn((float)s, 1000.0f);
        float b = __fadd_rn(a, 0.008f);
        float c = __fdiv_rn(b, 1.008f);
        float d = __fmul_rn(c, 0x1.921fb6p+1f);  // fl32(pi)
        float e = __fmul_rn(d, 0.5f);
        float cs = (float)cos((double)e);        // CR f32 cos
        ac[s] = __fmul_rn(cs, cs);
    }
    if (threadIdx.x == 0) {
        float hotf = -1e30f, coldf = 1e30f;
        for (int j = 0; j < 32; ++j) {
            float v = log_x0[j];
            hotf = fmaxf(hotf, v);
            coldf = fminf(coldf, v);
        }
        init2[0] = hotf;
        init2[1] = coldf;
        traj[64] = coldf;
    }
    __syncthreads();
    for (int s = threadIdx.x + 1; s <= t; s += blockDim.x)
        sig[s - 1] = __fsub_rn(1.0f, __fdiv_rn(ac[s], ac[s - 1]));
    __syncthreads();

    if (threadIdx.x < 32) {
        const int h = threadIdx.x;   // hot-bin position (einsum f32 sum order)
        float lh = init2[0];
        float lc = init2[1];
        for (int k = 0; k < t; ++k) {
            float sg = sig[k];
            float ph = (float)exp((double)lh);
            float pc = (float)exp((double)lc);
            float th = __fmul_rn(ph, 0.03125f);
            float tc = __fmul_rn(pc, 0.03125f);
            float acc = 0.0f;
            for (int i = 0; i < 32; ++i)
                acc = __fadd_rn(acc, (i == h) ? th : tc);
            float s1  = __fsub_rn(1.0f, sg);
            float sm  = __fmul_rn(sg, acc);
            float phn = __fadd_rn(__fmul_rn(s1, ph), sm);
            float pcn = __fadd_rn(__fmul_rn(s1, pc), sm);
            lh = cr_logf32(__fadd_rn(phn, 1e-8f));
            lc = cr_logf32(__fadd_rn(pcn, 1e-8f));
        }
        traj[h]      = lh;
        traj[32 + h] = lc;
    }
}

// Per-feature reduction body — byte-identical logic to round 8 (measured 2x).
__device__ __forceinline__ void process_feature(
        int vbase, float4 u4, float4 x4,
        const float* lh_s, const float* lc_s, float coldv,
        int lane8, float4* __restrict__ out) {
    const float uu0 = u4.x, uu1 = u4.y, uu2 = u4.z, uu3 = u4.w;
    const bool  h0 = x4.x > -1.0f, h1 = x4.y > -1.0f,
                h2 = x4.z > -1.0f, h3 = x4.w > -1.0f;

    // local top-2 cold u (first-index tie-break via strict >), hot pos/u
    int   hloc = -1;  float uhot = -1.0f;
    float t1u  = -1.0f; int t1i = 0; float t2u = -1.0f;
    const int ib = lane8 * 4;
    if (h0) { hloc = ib;   uhot = uu0; } else { t1u = uu0; t1i = ib; }
    if (h1) { hloc = ib+1; uhot = uu1; }
    else if (uu1 > t1u) { t2u = t1u; t1u = uu1; t1i = ib+1; }
    else if (uu1 > t2u) { t2u = uu1; }
    if (h2) { hloc = ib+2; uhot = uu2; }
    else if (uu2 > t1u) { t2u = t1u; t1u = uu2; t1i = ib+2; }
    else if (uu2 > t2u) { t2u = uu2; }
    if (h3) { hloc = ib+3; uhot = uu3; }
    else if (uu3 > t1u) { t2u = t1u; t1u = uu3; t1i = ib+3; }
    else if (uu3 > t2u) { t2u = uu3; }

    // 3-step merge across the 8-lane group
    #pragma unroll
    for (int m = 1; m < 8; m <<= 1) {
        float o1u = __shfl_xor(t1u, m);
        int   o1i = __shfl_xor(t1i, m);
        float o2u = __shfl_xor(t2u, m);
        int   ohl = __shfl_xor(hloc, m);
        float ouh = __shfl_xor(uhot, m);
        if (o1u > t1u)       { t2u = fmaxf(t1u, o2u); t1u = o1u; t1i = o1i; }
        else if (o1u == t1u) { t1i = min(t1i, o1i); t2u = t1u; }   // tie -> careful
        else                 { t2u = fmaxf(t2u, o1u); }
        hloc = max(hloc, ohl);
        uhot = fmaxf(uhot, ouh);
    }

    const int h = (hloc < 0) ? 0 : hloc;
    const float lh = lh_s[h];
    const float lc = lc_s[h];

    // fast hot-vs-cold compare
    const float s_hot  = lh + fast_g(uhot);
    const float s_cold = lc + fast_g(t1u);
    const float margin = s_hot - s_cold;
    int widx = (margin > 0.0f) ? h : t1i;

    const bool careful = (fabsf(margin) < 1e-3f) | ((t1u - t2u) < 1e-4f) | (hloc < 0);
    if (__builtin_expect(careful, 0)) {
        // exact round-3 path: CR-f64 g for all 4 local bins, group argmax
        float bs = -3.0e38f; int bi = 0;
        float s;
        s = __fadd_rn(h0 ? lh : lc, cr_g(uu0));
        if (s > bs) { bs = s; bi = ib; }
        s = __fadd_rn(h1 ? lh : lc, cr_g(uu1));
        if (s > bs) { bs = s; bi = ib+1; }
        s = __fadd_rn(h2 ? lh : lc, cr_g(uu2));
        if (s > bs) { bs = s; bi = ib+2; }
        s = __fadd_rn(h3 ? lh : lc, cr_g(uu3));
        if (s > bs) { bs = s; bi = ib+3; }
        #pragma unroll
        for (int m = 1; m < 8; m <<= 1) {
            float os = __shfl_xor(bs, m);
            int   oi = __shfl_xor(bi, m);
            if (os > bs || (os == bs && oi < bi)) { bs = os; bi = oi; }
        }
        widx = bi;
    }

    float4 o;
    o.x = (ib     == widx) ? 0.0f : coldv;
    o.y = (ib + 1 == widx) ? 0.0f : coldv;
    o.z = (ib + 2 == widx) ? 0.0f : coldv;
    o.w = (ib + 3 == widx) ? 0.0f : coldv;
    out[vbase] = o;                                      // 16B coalesced
}

__global__ void sample_kernel(const float4* __restrict__ log_x0,
                              const float4* __restrict__ u,
                              const float* __restrict__ traj,
                              float4* __restrict__ out,
                              int nfeat) {
    __shared__ float lh_s[32], lc_s[32];
    __shared__ float coldv_s;
    if (threadIdx.x < 32) {
        lh_s[threadIdx.x] = traj[threadIdx.x];
        lc_s[threadIdx.x] = traj[32 + threadIdx.x];
    }
    if (threadIdx.x == 0) coldv_s = traj[64];
    __syncthreads();
    const float coldv = coldv_s;

    const int lane8 = threadIdx.x & 7;
    const int g0 = (int)((blockIdx.x * blockDim.x + threadIdx.x) >> 3);
    const int gs = (int)((gridDim.x * blockDim.x) >> 3);
    const int gs2 = gs * 2;

    // 2x unrolled grid-stride: both features' loads issue before either
    // reduction chain runs (doubles in-flight memory per wave).
    for (int f = g0; f < nfeat; f += gs2) {
        const int fb = f + gs;
        const bool has_b = fb < nfeat;

        const int vba = f * 8 + lane8;
        const float4 u4a = u[vba];
        const float4 x4a = log_x0[vba];
        int vbb = vba;
        float4 u4b = u4a, x4b = x4a;
        if (has_b) {
            vbb = fb * 8 + lane8;
            u4b = u[vbb];
            x4b = log_x0[vbb];
        }

        process_feature(vba, u4a, x4a, lh_s, lc_s, coldv, lane8, out);
        if (has_b)
            process_feature(vbb, u4b, x4b, lh_s, lc_s, coldv, lane8, out);
    }
}

extern "C" void kernel_launch(void* const* d_in, const int* in_sizes, int n_in,
                              void* d_out, int out_size, void* d_ws, size_t ws_size,
                              hipStream_t stream) {
    const float* log_x0 = (const float*)d_in[0];
    const float* u      = (const float*)d_in[1];
    const int*   t_ptr  = (const int*)d_in[2];
    float* out  = (float*)d_out;
    float* traj = (float*)d_ws;

    const int nfeat = in_sizes[0] / 32;   // B*F = 1,048,576

    traj_kernel<<<1, 128, 0, stream>>>(log_x0, t_ptr, traj);

    sample_kernel<<<2048, 256, 0, stream>>>((const float4*)log_x0,
                                            (const float4*)u, traj,
                                            (float4*)out, nfeat);
}

// Round 11
// 135.098 us; speedup vs baseline: 2.2907x; 1.0010x over previous
//
#include <hip/hip_runtime.h>
#include <math.h>

// -----------------------------------------------------------------------------
// Round 11 = round 8/10 measured-good body + ONE delta: depth-1 CROSS-ITERATION
// prefetch. Round 10 issued loads in the same iteration that consumed them, so
// every iteration still paid full vmcnt latency (null result). Here iteration
// k issues k+1's loads, processes k's resident registers -> the vmcnt wait for
// k+1 lands AFTER ~1000 cycles of reduction work.
// Loop shape: counted for, inline guards, uniform trip count (65536 groups x
// 16 iters = 1,048,576 features exactly) — no lambda, no for(;;).
//
// Numerics (proven rounds 3/4/8/10): f32-faithful scan -> (lh,lc) per hot-bin
// position h; cold-bin score order == u order; one hot-vs-cold compare with
// hardened fast_g; guarded fallback to exact CR-f64 per-bin path.
// -----------------------------------------------------------------------------

__device__ __forceinline__ float cr_logf32(float x) { return (float)log((double)x); }

__device__ __forceinline__ float fast_g(float u) {
    // t3 = -log(u + 1e-30), piecewise (hardened near u->1):
    float w   = u - 1.0f;                      // exact for u in [0.5, 1]
    float p   = w * (1.0f - w * (0.5f - w * (0.33333334f - w * (0.25f -
                w * (0.2f - w * 0.16666667f)))));   // log1p(w), |w|<=0.1
    float t3p = 1e-30f - p;
    float t3l = 1e-30f - __logf(u + 1e-30f);
    float t3  = (u >= 0.9f) ? t3p : t3l;
    return -__logf(t3);
}

__device__ __forceinline__ float cr_g(float u) {
    float c0 = __fadd_rn(u, 1e-30f);
    float t2 = cr_logf32(c0);
    float t3 = __fadd_rn(-t2, 1e-30f);
    float t4 = cr_logf32(t3);
    return -t4;
}

// traj layout in d_ws: float lh[32], lc[32], coldv (index 64)
__global__ void traj_kernel(const float* __restrict__ log_x0,
                            const int* __restrict__ t_ptr,
                            float* __restrict__ traj) {
    __shared__ float ac[1001];
    __shared__ float sig[1000];
    __shared__ float init2[2];
    int t = *t_ptr;
    if (t > 1000) t = 1000;
    if (t < 0) t = 0;

    for (int s = threadIdx.x; s <= t; s += blockDim.x) {
        float a = __fdiv_rn((float)s, 1000.0f);
        float b = __fadd_rn(a, 0.008f);
        float c = __fdiv_rn(b, 1.008f);
        float d = __fmul_rn(c, 0x1.921fb6p+1f);  // fl32(pi)
        float e = __fmul_rn(d, 0.5f);
        float cs = (float)cos((double)e);        // CR f32 cos
        ac[s] = __fmul_rn(cs, cs);
    }
    if (threadIdx.x == 0) {
        float hotf = -1e30f, coldf = 1e30f;
        for (int j = 0; j < 32; ++j) {
            float v = log_x0[j];
            hotf = fmaxf(hotf, v);
            coldf = fminf(coldf, v);
        }
        init2[0] = hotf;
        init2[1] = coldf;
        traj[64] = coldf;
    }
    __syncthreads();
    for (int s = threadIdx.x + 1; s <= t; s += blockDim.x)
        sig[s - 1] = __fsub_rn(1.0f, __fdiv_rn(ac[s], ac[s - 1]));
    __syncthreads();

    if (threadIdx.x < 32) {
        const int h = threadIdx.x;   // hot-bin position (einsum f32 sum order)
        float lh = init2[0];
        float lc = init2[1];
        for (int k = 0; k < t; ++k) {
            float sg = sig[k];
            float ph = (float)exp((double)lh);
            float pc = (float)exp((double)lc);
            float th = __fmul_rn(ph, 0.03125f);
            float tc = __fmul_rn(pc, 0.03125f);
            float acc = 0.0f;
            for (int i = 0; i < 32; ++i)
                acc = __fadd_rn(acc, (i == h) ? th : tc);
            float s1  = __fsub_rn(1.0f, sg);
            float sm  = __fmul_rn(sg, acc);
            float phn = __fadd_rn(__fmul_rn(s1, ph), sm);
            float pcn = __fadd_rn(__fmul_rn(s1, pc), sm);
            lh = cr_logf32(__fadd_rn(phn, 1e-8f));
            lc = cr_logf32(__fadd_rn(pcn, 1e-8f));
        }
        traj[h]      = lh;
        traj[32 + h] = lc;
    }
}

// Per-feature reduction body — byte-identical logic to rounds 8/10 (measured).
__device__ __forceinline__ void process_feature(
        int vbase, float4 u4, float4 x4,
        const float* lh_s, const float* lc_s, float coldv,
        int lane8, float4* __restrict__ out) {
    const float uu0 = u4.x, uu1 = u4.y, uu2 = u4.z, uu3 = u4.w;
    const bool  h0 = x4.x > -1.0f, h1 = x4.y > -1.0f,
                h2 = x4.z > -1.0f, h3 = x4.w > -1.0f;

    // local top-2 cold u (first-index tie-break via strict >), hot pos/u
    int   hloc = -1;  float uhot = -1.0f;
    float t1u  = -1.0f; int t1i = 0; float t2u = -1.0f;
    const int ib = lane8 * 4;
    if (h0) { hloc = ib;   uhot = uu0; } else { t1u = uu0; t1i = ib; }
    if (h1) { hloc = ib+1; uhot = uu1; }
    else if (uu1 > t1u) { t2u = t1u; t1u = uu1; t1i = ib+1; }
    else if (uu1 > t2u) { t2u = uu1; }
    if (h2) { hloc = ib+2; uhot = uu2; }
    else if (uu2 > t1u) { t2u = t1u; t1u = uu2; t1i = ib+2; }
    else if (uu2 > t2u) { t2u = uu2; }
    if (h3) { hloc = ib+3; uhot = uu3; }
    else if (uu3 > t1u) { t2u = t1u; t1u = uu3; t1i = ib+3; }
    else if (uu3 > t2u) { t2u = uu3; }

    // 3-step merge across the 8-lane group
    #pragma unroll
    for (int m = 1; m < 8; m <<= 1) {
        float o1u = __shfl_xor(t1u, m);
        int   o1i = __shfl_xor(t1i, m);
        float o2u = __shfl_xor(t2u, m);
        int   ohl = __shfl_xor(hloc, m);
        float ouh = __shfl_xor(uhot, m);
        if (o1u > t1u)       { t2u = fmaxf(t1u, o2u); t1u = o1u; t1i = o1i; }
        else if (o1u == t1u) { t1i = min(t1i, o1i); t2u = t1u; }   // tie -> careful
        else                 { t2u = fmaxf(t2u, o1u); }
        hloc = max(hloc, ohl);
        uhot = fmaxf(uhot, ouh);
    }

    const int h = (hloc < 0) ? 0 : hloc;
    const float lh = lh_s[h];
    const float lc = lc_s[h];

    // fast hot-vs-cold compare
    const float s_hot  = lh + fast_g(uhot);
    const float s_cold = lc + fast_g(t1u);
    const float margin = s_hot - s_cold;
    int widx = (margin > 0.0f) ? h : t1i;

    const bool careful = (fabsf(margin) < 1e-3f) | ((t1u - t2u) < 1e-4f) | (hloc < 0);
    if (__builtin_expect(careful, 0)) {
        // exact round-3 path: CR-f64 g for all 4 local bins, group argmax
        float bs = -3.0e38f; int bi = 0;
        float s;
        s = __fadd_rn(h0 ? lh : lc, cr_g(uu0));
        if (s > bs) { bs = s; bi = ib; }
        s = __fadd_rn(h1 ? lh : lc, cr_g(uu1));
        if (s > bs) { bs = s; bi = ib+1; }
        s = __fadd_rn(h2 ? lh : lc, cr_g(uu2));
        if (s > bs) { bs = s; bi = ib+2; }
        s = __fadd_rn(h3 ? lh : lc, cr_g(uu3));
        if (s > bs) { bs = s; bi = ib+3; }
        #pragma unroll
        for (int m = 1; m < 8; m <<= 1) {
            float os = __shfl_xor(bs, m);
            int   oi = __shfl_xor(bi, m);
            if (os > bs || (os == bs && oi < bi)) { bs = os; bi = oi; }
        }
        widx = bi;
    }

    float4 o;
    o.x = (ib     == widx) ? 0.0f : coldv;
    o.y = (ib + 1 == widx) ? 0.0f : coldv;
    o.z = (ib + 2 == widx) ? 0.0f : coldv;
    o.w = (ib + 3 == widx) ? 0.0f : coldv;
    out[vbase] = o;                                      // 16B coalesced
}

__global__ void sample_kernel(const float4* __restrict__ log_x0,
                              const float4* __restrict__ u,
                              const float* __restrict__ traj,
                              float4* __restrict__ out,
                              int nfeat) {
    __shared__ float lh_s[32], lc_s[32];
    __shared__ float coldv_s;
    if (threadIdx.x < 32) {
        lh_s[threadIdx.x] = traj[threadIdx.x];
        lc_s[threadIdx.x] = traj[32 + threadIdx.x];
    }
    if (threadIdx.x == 0) coldv_s = traj[64];
    __syncthreads();
    const float coldv = coldv_s;

    const int lane8 = threadIdx.x & 7;
    const int g0 = (int)((blockIdx.x * blockDim.x + threadIdx.x) >> 3);
    const int gs = (int)((gridDim.x * blockDim.x) >> 3);     // 65536
    const int niter = (nfeat + gs - 1) / gs;                 // 16 exactly

    if (g0 >= nfeat) return;

    // depth-1 cross-iteration pipeline: iteration `it` issues it+1's loads,
    // then processes it's already-resident registers.
    int f = g0;
    float4 u4 = u[f * 8 + lane8];
    float4 x4 = log_x0[f * 8 + lane8];
    for (int it = 0; it < niter; ++it) {
        const int fn = f + gs;
        const bool more = (it + 1 < niter) && (fn < nfeat);  // wave-uniform
        float4 u4n, x4n;
        if (more) {
            u4n = u[fn * 8 + lane8];          // issued here, consumed next iter
            x4n = log_x0[fn * 8 + lane8];
        }
        process_feature(f * 8 + lane8, u4, x4, lh_s, lc_s, coldv, lane8, out);
        if (more) { u4 = u4n; x4 = x4n; }
        f = fn;
    }
}

extern "C" void kernel_launch(void* const* d_in, const int* in_sizes, int n_in,
                              void* d_out, int out_size, void* d_ws, size_t ws_size,
                              hipStream_t stream) {
    const float* log_x0 = (const float*)d_in[0];
    const float* u      = (const float*)d_in[1];
    const int*   t_ptr  = (const int*)d_in[2];
    float* out  = (float*)d_out;
    float* traj = (float*)d_ws;

    const int nfeat = in_sizes[0] / 32;   // B*F = 1,048,576

    traj_kernel<<<1, 128, 0, stream>>>(log_x0, t_ptr, traj);

    sample_kernel<<<2048, 256, 0, stream>>>((const float4*)log_x0,
                                            (const float4*)u, traj,
                                            (float4*)out, nfeat);
}